// Round 9
// baseline (7468.298 us; speedup 1.0000x reference)
//
#include <hip/hip_runtime.h>
#include <hip/hip_bf16.h>

#define AGENT __HIP_MEMORY_SCOPE_AGENT
#define RLX __ATOMIC_RELAXED
typedef unsigned long long u64t;

typedef _Float16 h2 __attribute__((ext_vector_type(2)));
union U32H2 { unsigned u; h2 h; };
__device__ __forceinline__ h2 uh(unsigned u){ U32H2 c; c.u=u; return c.h; }
__device__ __forceinline__ unsigned pk(float a, float b){
  U32H2 c; c.h = h2{(_Float16)a, (_Float16)b}; return c.u;
}
#define RCPF(x) __builtin_amdgcn_rcpf(x)

__device__ __forceinline__ float DOT2(unsigned a, unsigned b, float acc){
#if __has_builtin(__builtin_amdgcn_fdot2)
  return __builtin_amdgcn_fdot2(uh(a), uh(b), acc, false);
#else
  h2 x = uh(a), y = uh(b);
  acc = fmaf((float)x[0], (float)y[0], acc);
  return fmaf((float)x[1], (float)y[1], acc);
#endif
}
__device__ __forceinline__ float sigm(float x){ return RCPF(1.0f+__expf(-x)); }
__device__ __forceinline__ float ftanh(float x){ return 1.0f - 2.0f*RCPF(1.0f+__expf(x+x)); }

// ---------- value-tagged pub/poll (relaxed 64-bit agent atomics; R7/R8-proven) ----------
__device__ __forceinline__ void pubw(u64t* p, unsigned seq, unsigned data){
  __hip_atomic_store(p, ((u64t)seq<<32)|(u64t)data, RLX, AGENT);
}
template<int K>
__device__ __forceinline__ void waitN(const u64t* base, const int* off, unsigned seq,
                                      unsigned* out, unsigned* kf){
  long n=0;
  for(;;){
    u64t v[K]; bool ok=true;
    #pragma unroll
    for(int k=0;k<K;k++) v[k]=__hip_atomic_load(base+off[k], RLX, AGENT);
    #pragma unroll
    for(int k=0;k<K;k++) ok &= ((unsigned)(v[k]>>32)==seq);
    if(ok){
      #pragma unroll
      for(int k=0;k<K;k++) out[k]=(unsigned)v[k];
      return;
    }
    __builtin_amdgcn_s_sleep(1);
    if((++n&255)==0){
      if(__hip_atomic_load(kf,RLX,AGENT)!=0u) break;
      if(n>300000L){ __hip_atomic_store(kf,1u,RLX,AGENT); break; }
    }
  }
  #pragma unroll
  for(int k=0;k<K;k++) out[k]=0u;
}

// ---------------- one-time weight folds (f32 GEMM inputs) ----------------
__global__ void k_fold(const float* __restrict__ Wp, const float* __restrict__ Wq,
                       const float* __restrict__ Wg,
                       float* __restrict__ WpT, float* __restrict__ WqT,
                       float* __restrict__ WgupT, float* __restrict__ WgcT)
{
  int i0 = blockIdx.x*blockDim.x+threadIdx.x;
  int st = gridDim.x*blockDim.x;
  for(int o=i0;o<512*150;o+=st){ int h=o%150, i=o/150;
    WpT[o]=Wp[h*1024+i]+Wp[h*1024+512+i];
    WqT[o]=Wq[h*1024+i]+Wq[h*1024+512+i]; }
  for(int o=i0;o<512*1024;o+=st){ int i=o&511, j=o>>9;
    size_t rb=(size_t)(1024+j)*2048;
    WgupT[(size_t)i*1024+j]=Wg[rb+i]+Wg[rb+512+i];
    WgcT [(size_t)i*1024+j]=Wg[rb+1024+i]+Wg[rb+1536+i]; }
}

// pair layouts: WihT[jp*456+k] (coalesced in k), WhhP[p*456+k], WvU[p*152+h]
__global__ void k_fold2(const float* __restrict__ Wih,
                        const float* __restrict__ Whh, const float* __restrict__ Wv,
                        unsigned* __restrict__ WihT,
                        unsigned* __restrict__ WhhP, unsigned* __restrict__ WvU)
{
  int i0 = blockIdx.x*blockDim.x+threadIdx.x;
  int st = gridDim.x*blockDim.x;
  for(int o=i0;o<512*456;o+=st){ int k=o%456, jp=o/456;
    unsigned v = 0u;
    if(k<450) v = pk(Wih[(size_t)k*1024+2*jp], Wih[(size_t)k*1024+2*jp+1]);
    WihT[o] = v; }
  for(int o=i0;o<76*456;o+=st){ int k=o%456, p=o/456;
    float x=0.f,y=0.f;
    if(k<450){ if(2*p<150) x=Whh[k*150+2*p]; if(2*p+1<150) y=Whh[k*150+2*p+1]; }
    WhhP[o]=pk(x,y); }
  for(int o=i0;o<76*152;o+=st){ int h=o%152, p=o/152;
    float x=0.f,y=0.f;
    if(h<150){ if(2*p<150) x=Wv[h*150+2*p]; if(2*p+1<150) y=Wv[h*150+2*p+1]; }
    WvU[o]=pk(x,y); }
}

// uq (q,b,i) f32 -> uqP[(b*512+i)*128 + qp] pairs over q
__global__ __launch_bounds__(256) void k_uqp(const float* __restrict__ uq, unsigned* __restrict__ uqP){
  __shared__ float Al[32*512];
  int b = blockIdx.x, qt = blockIdx.y, tid = threadIdx.x;
  for(int o4=tid;o4<4096;o4+=256){ int m=o4>>7, i4=o4&127;
    ((float4*)Al)[o4] = *(const float4*)&uq[(size_t)(qt*32+m)*16384 + b*512 + i4*4]; }
  __syncthreads();
  for(int o=tid;o<8192;o+=256){ int i=o>>4, p=o&15;
    uqP[((size_t)b*512+i)*128 + qt*16 + p] = pk(Al[(2*p)*512+i], Al[(2*p+1)*512+i]); }
}

// precompute GEMMs: MODE0 Wuph[b][t][152] ; MODE3 WqUqh[b][q][152] ; MODE4 Gup3[b][t][1024]
template<int MODE>
__global__ __launch_bounds__(256) void k_gemm(const float* __restrict__ A,
   const float* __restrict__ WT, _Float16* __restrict__ oH, int N)
{
  __shared__ float Al[32*512];
  int mt=blockIdx.x, nt=blockIdx.y, tid=threadIdx.x;
  const float* Ab = A + (size_t)mt*16384;
  for(int o=tid;o<4096;o+=256) ((float4*)Al)[o]=((const float4*)Ab)[o];
  __syncthreads();
  int n = nt*256+tid;
  if(n>=N) return;
  float acc[32];
  #pragma unroll
  for(int m=0;m<32;m++) acc[m]=0.f;
  const float* wp = WT + n;
  #pragma unroll 2
  for(int k=0;k<512;k+=2){
    float w0 = wp[(size_t)k*N], w1 = wp[(size_t)(k+1)*N];
    #pragma unroll
    for(int m=0;m<32;m++) acc[m]=fmaf(w0, Al[m*512+k], acc[m]);
    #pragma unroll
    for(int m=0;m<32;m++) acc[m]=fmaf(w1, Al[m*512+k+1], acc[m]);
  }
  if(MODE==0){
    #pragma unroll
    for(int m=0;m<32;m++) oH[((size_t)m*512 + mt)*152 + n] = (_Float16)acc[m];
  } else if(MODE==3){
    #pragma unroll
    for(int m=0;m<32;m++) oH[((size_t)m*256 + mt)*152 + n] = (_Float16)acc[m];
  } else {
    #pragma unroll
    for(int m=0;m<32;m++) oH[((size_t)m*512 + mt)*1024 + n] = (_Float16)acc[m];
  }
}

// M[b] = uq[b] @ WgcT : Mp[(b*1024+j)*128 + qp]
__global__ __launch_bounds__(256) void k_gemmM(const float* __restrict__ uq,
   const float* __restrict__ WgcT, unsigned* __restrict__ Mp)
{
  __shared__ float Al[32*512];
  int b=blockIdx.x, qt=blockIdx.y, nt=blockIdx.z, tid=threadIdx.x;
  for(int o4=tid;o4<4096;o4+=256){ int m=o4>>7, i4=o4&127;
    ((float4*)Al)[o4] = *(const float4*)&uq[(size_t)(qt*32+m)*16384 + b*512 + i4*4]; }
  __syncthreads();
  int n = nt*256+tid;
  float acc[32];
  #pragma unroll
  for(int m=0;m<32;m++) acc[m]=0.f;
  const float* wp = WgcT + n;
  #pragma unroll 2
  for(int k=0;k<512;k+=2){
    float w0 = wp[(size_t)k*1024], w1 = wp[(size_t)(k+1)*1024];
    #pragma unroll
    for(int m=0;m<32;m++) acc[m]=fmaf(w0, Al[m*512+k], acc[m]);
    #pragma unroll
    for(int m=0;m<32;m++) acc[m]=fmaf(w1, Al[m*512+k+1], acc[m]);
  }
  #pragma unroll
  for(int p=0;p<16;p++)
    Mp[((size_t)b*1024 + n)*128 + qt*16 + p] = pk(acc[2*p], acc[2*p+1]);
}

__global__ void k_init(unsigned* comm){
  int i = blockIdx.x*blockDim.x + threadIdx.x;
  if(i < 66052) comm[i] = 0u;
}

// ---------------- persistent: 160 blocks, 2-hop, register-pinned weights ----------------
struct __align__(16) SMO {
  unsigned WvU[76*152];
  unsigned WqUq[256*76];
  unsigned wup[80], vp[80];
  float V[152], v[152], w2[152], s[256], a[256];
  float gi[452], rgh[2][452], bi[452], bh[452];
};
struct __align__(16) SMW {
  unsigned M[128*257];         // [qp][jl] stride 257 (bank-tuned)
  unsigned a2[128], gup[128], cpr[128];
  float ccf[128], Gc[256], c_f[256], rgi[2][452];
};
union SMU { SMO o; SMW w; };

__global__ __launch_bounds__(1024) void persist(
  const unsigned* __restrict__ uqP,   const unsigned* __restrict__ Mp,
  const unsigned* __restrict__ Gup3u, const unsigned* __restrict__ Wuphu,
  const unsigned* __restrict__ WqUqhu, const unsigned* __restrict__ WihTu,
  const unsigned* __restrict__ WhhP,  const unsigned* __restrict__ WvUg,
  const float* __restrict__ v0, const float* __restrict__ Vin,
  const float* __restrict__ bih, const float* __restrict__ bhh,
  u64t* aP, u64t* giP, unsigned* kf,
  float* __restrict__ dout)
{
  extern __shared__ char smraw[];
  SMU& S = *reinterpret_cast<SMU*>(smraw);
  const int tid = threadIdx.x;
  const int bid = blockIdx.x;

  if(bid < 32){
    // ================= OWNER (per b): GRU + gh(reg-Whh), w2, s, softmax -> aP =================
    const int b = bid;
    for(int o=tid;o<11552;o+=1024) S.o.WvU[o]=WvUg[o];
    for(int o=tid;o<19456;o+=1024){ int q=o/76,w=o%76;
      S.o.WqUq[o]=WqUqhu[((size_t)b*256+q)*76+w]; }
    for(int o=tid;o<152;o+=1024){
      S.o.V[o]=(o<150)?Vin[b*150+o]:0.f;
      S.o.v[o]=(o<150)?v0[b*150+o]:0.f; }
    for(int o=tid;o<452;o+=1024){
      S.o.bi[o]=(o<450)?bih[o]:0.f;
      S.o.bh[o]=(o<450)?bhh[o]:0.f; }
    // register-pinned Whh slice (step-invariant per thread)
    unsigned whh[38];
    {
      int k=tid&511, half=tid>>9;
      #pragma unroll
      for(int p=0;p<38;p++){
        int pp=half*38+p;
        whh[p] = (k<450 && pp<76)? WhhP[(size_t)pp*456+k] : 0u;
      }
    }
    __syncthreads();

    const int gib = b*904;   // b*4*226
    for(int t=0;t<512;++t){
      if(tid<76) S.o.wup[tid]=Wuphu[((size_t)b*512+t)*76+tid];
      if(t>0){
        if(tid<225){
          int off[4]={gib+tid, gib+226+tid, gib+452+tid, gib+678+tid};
          unsigned gv[4];
          waitN<4>(giP,off,(unsigned)t,gv,kf);
          float g0=0.f,g1=0.f;
          #pragma unroll
          for(int k=0;k<4;k++){ h2 x=uh(gv[k]); g0+=(float)x[0]; g1+=(float)x[1]; }
          S.o.gi[2*tid]=g0; S.o.gi[2*tid+1]=g1;
        }
        __syncthreads();
        if(tid<150){
          float gh0=S.o.rgh[0][tid]+S.o.rgh[1][tid]+S.o.bh[tid];
          float gh1=S.o.rgh[0][150+tid]+S.o.rgh[1][150+tid]+S.o.bh[150+tid];
          float gh2=S.o.rgh[0][300+tid]+S.o.rgh[1][300+tid]+S.o.bh[300+tid];
          float rg=sigm(S.o.gi[tid]+S.o.bi[tid] + gh0);
          float zg=sigm(S.o.gi[150+tid]+S.o.bi[150+tid] + gh1);
          float ng=ftanh(S.o.gi[300+tid]+S.o.bi[300+tid] + rg*gh2);
          float vn=fmaf(zg, S.o.v[tid]-ng, ng);
          S.o.v[tid]=vn;
          dout[((size_t)(t-1)*32+b)*150+tid]=vn;
        }
        __syncthreads();
      }
      if(tid<76) S.o.vp[tid]=pk(S.o.v[2*tid], S.o.v[2*tid+1]);
      __syncthreads();
      // w2 = wup + Wv.v
      if(tid<608){
        int h=tid>>2, qd=tid&3;
        float acc=0.f;
        if(h<150){
          #pragma unroll
          for(int p=qd*19;p<qd*19+19;p++) acc=DOT2(S.o.WvU[p*152+h], S.o.vp[p], acc);
        }
        acc+=__shfl_xor(acc,1,64); acc+=__shfl_xor(acc,2,64);
        if(h<150&&qd==0){ h2 ww=uh(S.o.wup[h>>1]); S.o.w2[h]=acc+(float)ww[h&1]; }
      }
      __syncthreads();
      // s[q] = sum_h V[h] tanh(w2[h]+WqUq[q,h])
      {
        int q=tid>>2, hq=tid&3;
        int hp0=hq*19, hp1=(hq==3)?75:hp0+19;
        float acc=0.f;
        for(int hp=hp0;hp<hp1;hp++){
          h2 wp=uh(S.o.WqUq[q*76+hp]);
          acc=fmaf(S.o.V[2*hp],   ftanh(S.o.w2[2*hp]  +(float)wp[0]), acc);
          acc=fmaf(S.o.V[2*hp+1], ftanh(S.o.w2[2*hp+1]+(float)wp[1]), acc);
        }
        acc+=__shfl_xor(acc,1,64); acc+=__shfl_xor(acc,2,64);
        if(hq==0) S.o.s[q]=acc;
      }
      __syncthreads();
      if(tid<64){
        float x0=S.o.s[tid],x1=S.o.s[tid+64],x2=S.o.s[tid+128],x3=S.o.s[tid+192];
        float mx=fmaxf(fmaxf(x0,x1),fmaxf(x2,x3));
        #pragma unroll
        for(int o=1;o<64;o<<=1) mx=fmaxf(mx,__shfl_xor(mx,o,64));
        float e0=__expf(x0-mx),e1=__expf(x1-mx),e2=__expf(x2-mx),e3=__expf(x3-mx);
        float sm=e0+e1+e2+e3;
        #pragma unroll
        for(int o=1;o<64;o<<=1) sm+=__shfl_xor(sm,o,64);
        float rs=RCPF(sm);
        S.o.a[tid]=e0*rs; S.o.a[tid+64]=e1*rs; S.o.a[tid+128]=e2*rs; S.o.a[tid+192]=e3*rs;
      }
      __syncthreads();
      if(tid<128) pubw(aP+b*128+tid,(unsigned)(t+1), pk(S.o.a[2*tid],S.o.a[2*tid+1]));
      // gh = Whh.v from registers (overlapped with worker phase)
      {
        int k=tid&511, half=tid>>9;
        if(k<450){
          float ah=0.f;
          #pragma unroll
          for(int p=0;p<38;p++) ah=DOT2(whh[p], S.o.vp[(half*38+p)<76 ? half*38+p : 0], ah);
          S.o.rgh[half][k]=ah;
        }
      }
      // rgh consumed after next iteration's post-poll __syncthreads
    }
    // epilogue: v_512 -> dout[511]
    if(tid<225){
      int off[4]={gib+tid, gib+226+tid, gib+452+tid, gib+678+tid};
      unsigned gv[4];
      waitN<4>(giP,off,512u,gv,kf);
      float g0=0.f,g1=0.f;
      #pragma unroll
      for(int k=0;k<4;k++){ h2 x=uh(gv[k]); g0+=(float)x[0]; g1+=(float)x[1]; }
      S.o.gi[2*tid]=g0; S.o.gi[2*tid+1]=g1;
    }
    __syncthreads();
    if(tid<150){
      float gh0=S.o.rgh[0][tid]+S.o.rgh[1][tid]+S.o.bh[tid];
      float gh1=S.o.rgh[0][150+tid]+S.o.rgh[1][150+tid]+S.o.bh[150+tid];
      float gh2=S.o.rgh[0][300+tid]+S.o.rgh[1][300+tid]+S.o.bh[300+tid];
      float rg=sigm(S.o.gi[tid]+S.o.bi[tid] + gh0);
      float zg=sigm(S.o.gi[150+tid]+S.o.bi[150+tid] + gh1);
      float ng=ftanh(S.o.gi[300+tid]+S.o.bi[300+tid] + rg*gh2);
      dout[((size_t)511*32+b)*150+tid]=fmaf(zg, S.o.v[tid]-ng, ng);
    }

  } else {
    // ================= WORKER (4 per b): cc, Gc=a.M, gate, c_, gi (reg-Wih) =================
    const int wid = bid-32;
    const int b = wid>>2, s = wid&3;
    for(int o=tid;o<32768;o+=1024){
      int qp=o&127, jl=o>>7;
      int j = s*128 + (jl&127) + ((jl>>7)<<9);
      S.w.M[qp*257+jl] = Mp[((size_t)b*1024+j)*128+qp];
    }
    // register-pinned Wih slice (step-invariant per thread): 64 jp-pairs
    unsigned wih[64];
    {
      int k=tid&511, half=tid>>9;
      #pragma unroll
      for(int m=0;m<64;m++){
        int jpg = half*256 + s*64 + m;
        wih[m] = (k<450)? WihTu[(size_t)jpg*456+k] : 0u;
      }
    }
    __syncthreads();
    const size_t uqbase = ((size_t)b*512 + s*128)*128;
    for(int t=0;t<512;++t){
      if(tid<128){
        int wi = (tid<64)? (s*64+tid) : (256+s*64+tid-64);
        S.w.gup[tid] = Gup3u[((size_t)b*512+t)*512 + wi];
      }
      if(tid<128){
        int off[1]={b*128+tid};
        unsigned av[1];
        waitN<1>(aP,off,(unsigned)(t+1),av,kf);
        S.w.a2[tid]=av[0];
      }
      __syncthreads();
      // cc[i] = sum_qp dot2(a2, uq[i])  (uq slice streamed from L2)
      {
        int i=tid>>3, q8=tid&7;
        float acc=0.f;
        const unsigned* up = uqP + uqbase + (size_t)i*128;
        #pragma unroll 4
        for(int kk=0;kk<16;kk++){
          int qp=kk*8+q8;
          acc=DOT2(S.w.a2[qp], up[qp], acc);
        }
        acc+=__shfl_xor(acc,1,64); acc+=__shfl_xor(acc,2,64); acc+=__shfl_xor(acc,4,64);
        if(q8==0) S.w.ccf[i]=acc;
      }
      // Gc[jl] = sum_qp dot2(a2, M[qp][jl])
      {
        int jl=tid>>2, qc=tid&3;
        float acc=0.f;
        #pragma unroll 8
        for(int kk=0;kk<32;kk++){
          int qp=kk*4+qc;
          acc=DOT2(S.w.a2[qp], S.w.M[qp*257+jl], acc);
        }
        acc+=__shfl_xor(acc,1,64); acc+=__shfl_xor(acc,2,64);
        if(qc==0) S.w.Gc[jl]=acc;
      }
      __syncthreads();
      // c_[jl] = sigm(Gc+gup)*cc[jl&127]
      if(tid<256){
        h2 gv=uh(S.w.gup[tid>>1]);
        float g=sigm(S.w.Gc[tid]+(float)gv[tid&1]);
        S.w.c_f[tid]=g*S.w.ccf[tid&127];
      }
      __syncthreads();
      if(tid<128) S.w.cpr[tid]=pk(S.w.c_f[2*tid],S.w.c_f[2*tid+1]);
      __syncthreads();
      // gi partial from register-pinned Wih + LDS-broadcast cpr
      {
        int k=tid&511, half=tid>>9;
        float acc=0.f;
        #pragma unroll
        for(int m=0;m<64;m++) acc=DOT2(wih[m], S.w.cpr[half*64+m], acc);
        if(k<450) S.w.rgi[half][k]=acc;
      }
      __syncthreads();
      if(tid<225){
        float g0=S.w.rgi[0][2*tid]+S.w.rgi[1][2*tid];
        float g1=S.w.rgi[0][2*tid+1]+S.w.rgi[1][2*tid+1];
        pubw(giP + ((size_t)b*4+s)*226 + tid, (unsigned)(t+1), pk(g0,g1));
      }
    }
  }
}

// ---------------- host ----------------
extern "C" void kernel_launch(void* const* d_in, const int* in_sizes, int n_in,
                              void* d_out, int out_size, void* d_ws, size_t ws_size,
                              hipStream_t stream)
{
  const float* up  = (const float*)d_in[0];
  const float* uq  = (const float*)d_in[1];
  const float* v0  = (const float*)d_in[2];
  const float* Vm  = (const float*)d_in[3];
  const float* Wp  = (const float*)d_in[4];
  const float* Wq  = (const float*)d_in[5];
  const float* Wv  = (const float*)d_in[6];
  const float* Wg  = (const float*)d_in[7];
  const float* W_ih= (const float*)d_in[8];
  const float* W_hh= (const float*)d_in[9];
  const float* b_ih= (const float*)d_in[10];
  const float* b_hh= (const float*)d_in[11];
  float* dout = (float*)d_out;
  char* wsb = (char*)d_ws;

  size_t off = 0;
  auto alloc = [&](size_t bytes)->size_t{ size_t p = off; off = (off + bytes + 255) & ~(size_t)255; return p; };
  size_t oWgupT = alloc((size_t)512*1024*4);      // 2MB; comm aliases after gemms
  size_t oWgcT  = alloc((size_t)512*1024*4);
  size_t oWuph  = alloc((size_t)32*512*152*2);
  size_t oWqUqh = alloc((size_t)32*256*152*2);
  size_t oWihT  = alloc((size_t)512*456*4);
  size_t oWhhP  = alloc((size_t)76*456*4);
  size_t oWvU   = alloc((size_t)76*152*4);
  size_t oUqP   = alloc((size_t)32*512*128*4);
  size_t oMp    = alloc((size_t)32*1024*128*4);
  size_t oGup3  = alloc((size_t)32*512*1024*2);   // WpT/WqT alias (dead before write)
  if(ws_size < off) return;

  float*    WgupT = (float*)(wsb + oWgupT);
  float*    WgcT  = (float*)(wsb + oWgcT);
  _Float16* Wuph  = (_Float16*)(wsb + oWuph);
  _Float16* WqUqh = (_Float16*)(wsb + oWqUqh);
  unsigned* WihT  = (unsigned*)(wsb + oWihT);
  unsigned* WhhP  = (unsigned*)(wsb + oWhhP);
  unsigned* WvU   = (unsigned*)(wsb + oWvU);
  unsigned* uqP   = (unsigned*)(wsb + oUqP);
  unsigned* Mp    = (unsigned*)(wsb + oMp);
  _Float16* Gup3  = (_Float16*)(wsb + oGup3);
  float* WpT = (float*)(wsb + oGup3);
  float* WqT = (float*)(wsb + oGup3 + 307456);

  // tagged pubs alias the (dead-after-gemms) WgupT region
  u64t* comm64 = (u64t*)(wsb + oWgupT);
  u64t* aP  = comm64;              // 32*128 = 4096
  u64t* giP = comm64 + 4096;       // 32*4*226 = 28928
  unsigned* kf = (unsigned*)(comm64 + 33024);

  k_fold <<<256,256,0,stream>>>(Wp,Wq,Wg, WpT,WqT,WgupT,WgcT);
  k_fold2<<<256,256,0,stream>>>(W_ih, W_hh, Wv, WihT, WhhP, WvU);
  k_uqp  <<<dim3(32,8),256,0,stream>>>(uq, uqP);
  k_gemm<0><<<dim3(512,1),256,0,stream>>>(up, WpT, Wuph, 150);
  k_gemm<3><<<dim3(256,1),256,0,stream>>>(uq, WqT, WqUqh, 150);
  k_gemm<4><<<dim3(512,4),256,0,stream>>>(up, WgupT, Gup3, 1024);  // WpT/WqT dead now
  k_gemmM<<<dim3(32,8,4),256,0,stream>>>(uq, WgcT, Mp);
  k_init <<<65,1024,0,stream>>>((unsigned*)comm64);                 // WgupT dead now

  int smem = (int)sizeof(SMU);
  hipFuncSetAttribute((const void*)persist, hipFuncAttributeMaxDynamicSharedMemorySize, smem);
  const unsigned* Gup3u  = (const unsigned*)Gup3;
  const unsigned* Wuphu  = (const unsigned*)Wuph;
  const unsigned* WqUqhu = (const unsigned*)WqUqh;
  void* ka[16] = { (void*)&uqP, (void*)&Mp, (void*)&Gup3u, (void*)&Wuphu, (void*)&WqUqhu,
                   (void*)&WihT, (void*)&WhhP, (void*)&WvU,
                   (void*)&v0, (void*)&Vm, (void*)&b_ih, (void*)&b_hh,
                   (void*)&aP, (void*)&giP, (void*)&kf, (void*)&dout };
  hipLaunchCooperativeKernel((const void*)persist, dim3(160), dim3(1024), ka,
                             (unsigned)smem, stream);
}